// Round 2
// 721.507 us; speedup vs baseline: 1.1104x; 1.1104x over previous
//
#include <hip/hip_runtime.h>
#include <stdint.h>

typedef __bf16 bf16_t;
typedef __bf16 bf16x8 __attribute__((ext_vector_type(8)));
typedef float floatx4 __attribute__((ext_vector_type(4)));

#define N_ROWS 16384
#define D_IN   2048
#define D_OUT  2048
#define EPSF   1e-6f
#define TINYF  1e-15f

// GEMM geometry: 256x256 tile, BK=64, 8 waves (512 thr), 2-deep LDS double buffer
#define BM 256
#define BN 256
#define BK 64
#define NT 96   // 3 precision segments * (2048/64) k-tiles

// async global->LDS, 16B/lane; LDS base wave-uniform, lane*16 implicit
__device__ __forceinline__ void load_lds16(const void* g, void* l) {
    __builtin_amdgcn_global_load_lds(
        (const __attribute__((address_space(1))) unsigned int*)(const unsigned int*)g,
        (__attribute__((address_space(3))) unsigned int*)(unsigned int*)l,
        16, 0, 0);
}

// ---------- Kernel 0: split W (f32) into bf16 hi/lo planes ----------
__global__ __launch_bounds__(256) void pvfc_wsplit(
    const float* __restrict__ W, bf16_t* __restrict__ Wh, bf16_t* __restrict__ Wl)
{
    const size_t i = ((size_t)blockIdx.x * 256 + threadIdx.x) * 8;
    float4 a = *(const float4*)(W + i);
    float4 c = *(const float4*)(W + i + 4);
    float v[8] = {a.x, a.y, a.z, a.w, c.x, c.y, c.z, c.w};
    bf16x8 hv, lv;
#pragma unroll
    for (int j = 0; j < 8; ++j) {
        const bf16_t h = (bf16_t)v[j];
        hv[j] = h;
        lv[j] = (bf16_t)(v[j] - (float)h);
    }
    *(bf16x8*)(Wh + i) = hv;
    *(bf16x8*)(Wl + i) = lv;
}

// ---------- Kernel 1: v = asinh(||x||)/||x|| * x, split into bf16 hi/lo ----------
// A layout: [rows][4096] bf16 : cols 0..2047 = v_hi, 2048..4095 = v_lo
__global__ __launch_bounds__(256) void pvfc_prologue(
    const float* __restrict__ x, bf16_t* __restrict__ Ap)
{
    __shared__ float red[4];
    const int row = blockIdx.x, tid = threadIdx.x;
    const int lane = tid & 63, wave = tid >> 6;

    const float* xr = x + (size_t)row * D_IN + tid * 8;
    float4 a = *(const float4*)xr;
    float4 c = *(const float4*)(xr + 4);
    float v[8] = {a.x, a.y, a.z, a.w, c.x, c.y, c.z, c.w};

    float s = 0.f;
#pragma unroll
    for (int i = 0; i < 8; ++i) s += v[i] * v[i];
#pragma unroll
    for (int off = 32; off > 0; off >>= 1) s += __shfl_down(s, off, 64);
    if (lane == 0) red[wave] = s;
    __syncthreads();
    const float s2  = red[0] + red[1] + red[2] + red[3];
    const float nrm = sqrtf(s2);
    const float coef = asinhf(nrm) / fmaxf(nrm, EPSF);

    bf16x8 hv, lv;
#pragma unroll
    for (int j = 0; j < 8; ++j) {
        const float vi = coef * v[j];
        const bf16_t h = (bf16_t)vi;
        hv[j] = h;
        lv[j] = (bf16_t)(vi - (float)h);
    }
    bf16_t* ar = Ap + (size_t)row * (2 * D_IN);
    *(bf16x8*)(ar + tid * 8)         = hv;
    *(bf16x8*)(ar + D_IN + tid * 8)  = lv;
}

// ---------- Kernel 2: U = Ah.Wh^T + Al.Wh^T + Ah.Wl^T, 8-phase 256^2 schedule ----------
// T3+T4: 4 sub-phases per K-tile, counted vmcnt(2) once per tile (never 0) so the
// global_load_lds prefetch stream stays in flight across barriers.
// T2: chunk ^= (row&7) XOR swizzle (pre-swizzled global src + swizzled ds_read).
// T5: setprio around each 16-MFMA cluster.
// T1: col-panel = bid%8 pins each 256-col W panel (2MB hi+lo) to one XCD's L2.
#define BAR __builtin_amdgcn_s_barrier()
#define WAIT_LGKM0 do { asm volatile("s_waitcnt lgkmcnt(0)" ::: "memory"); \
                        __builtin_amdgcn_sched_barrier(0); } while (0)
#define WAIT_VM2   do { asm volatile("s_waitcnt vmcnt(2)" ::: "memory");   \
                        __builtin_amdgcn_sched_barrier(0); } while (0)

#define LOAD_A(buf, qm)                                                        \
    _Pragma("unroll")                                                          \
    for (int i = 0; i < 4; ++i) {                                              \
        const int rA = wm * 128 + ((qm) * 4 + i) * 16 + m16;                   \
        _Pragma("unroll")                                                      \
        for (int ks = 0; ks < 2; ++ks)                                         \
            af[i][ks] = *(const bf16x8*)&As[buf][rA * BK +                     \
                                                 (((ks * 4 + quad) ^ sw) * 8)];\
    }

#define LOAD_B(buf, qn, bq)                                                    \
    _Pragma("unroll")                                                          \
    for (int j = 0; j < 2; ++j) {                                              \
        const int rB = wn * 64 + ((qn) * 2 + j) * 16 + m16;                    \
        _Pragma("unroll")                                                      \
        for (int ks = 0; ks < 2; ++ks)                                         \
            bq[j][ks] = *(const bf16x8*)&Bs[buf][rB * BK +                     \
                                                 (((ks * 4 + quad) ^ sw) * 8)];\
    }

#define MFMA_Q(qm, qn, bq)                                                     \
    do {                                                                       \
        __builtin_amdgcn_sched_barrier(0);                                     \
        __builtin_amdgcn_s_setprio(1);                                         \
        _Pragma("unroll")                                                      \
        for (int ks = 0; ks < 2; ++ks)                                         \
            _Pragma("unroll")                                                  \
            for (int i = 0; i < 4; ++i)                                        \
                _Pragma("unroll")                                              \
                for (int j = 0; j < 2; ++j)                                    \
                    acc[(qm) * 4 + i][(qn) * 2 + j] =                          \
                        __builtin_amdgcn_mfma_f32_16x16x32_bf16(               \
                            af[i][ks], bq[j][ks],                              \
                            acc[(qm) * 4 + i][(qn) * 2 + j], 0, 0, 0);         \
        __builtin_amdgcn_s_setprio(0);                                         \
        __builtin_amdgcn_sched_barrier(0);                                     \
    } while (0)

__global__ __launch_bounds__(512, 2) void pvfc_gemm(
    const bf16_t* __restrict__ A,   // [rows][4096] hi|lo
    const bf16_t* __restrict__ Wh, const bf16_t* __restrict__ Wl, // [2048][2048]
    float* __restrict__ U)          // [rows][2048] f32
{
    __shared__ __align__(16) bf16_t As[2][BM * BK];  // 64 KiB
    __shared__ __align__(16) bf16_t Bs[2][BN * BK];  // 64 KiB

    const int tid  = threadIdx.x;
    const int wave = tid >> 6, lane = tid & 63;
    const int bid  = blockIdx.x;
    const int colBase = (bid & 7) * BN;   // bid%8 == XCD: W panel L2-resident
    const int rowBase = (bid >> 3) * BM;

    const int wm = wave >> 2, wn = wave & 3;        // 2x4 wave grid, 128x64/wave
    const int m16 = lane & 15, quad = lane >> 4;
    const int sw  = m16 & 7;                        // read-side xor key

    // staging: 512 threads cover 64 rows x 128B per load; src pre-swizzled
    const int sRow = tid >> 3;                      // 0..63
    const int sCol = ((tid & 7) ^ (sRow & 7)) * 8;  // logical chunk for linear dest
    const int ldsOff = wave * 512;                  // wave-uniform dest (elements)

    floatx4 acc[8][4];
    bf16x8 af[4][2], bq0[2][2], bq1[2][2];
    const floatx4 z = {0.f, 0.f, 0.f, 0.f};
#pragma unroll
    for (int i = 0; i < 8; ++i)
#pragma unroll
        for (int j = 0; j < 4; ++j) acc[i][j] = z;

    // half-tile stagers (2 x global_load_lds each); tile clamped at tail (writes
    // land in a buffer that is never read again -> safe, addresses in-bounds)
    auto stageA = [&](int tile, int half, int buf) {
        const int tt  = tile < NT ? tile : NT - 1;
        const int seg = tt >> 5;                    // 0:(Ah,Wh) 1:(Al,Wh) 2:(Ah,Wl)
        const size_t off = (size_t)((seg == 1) ? D_IN : 0) + (size_t)(tt & 31) * BK;
        const bf16_t* src = A + (size_t)(rowBase + half * 128 + sRow) * (2 * D_IN)
                              + off + sCol;
        bf16_t* dst = &As[buf][half * 128 * BK + ldsOff];
        load_lds16(src, dst);
        load_lds16(src + (size_t)64 * (2 * D_IN), dst + 64 * BK);
    };
    auto stageB = [&](int tile, int half, int buf) {
        const int tt  = tile < NT ? tile : NT - 1;
        const bf16_t* Wp = ((tt >> 5) == 2) ? Wl : Wh;
        const int k0 = (tt & 31) * BK;
        const bf16_t* src = Wp + (size_t)(colBase + half * 128 + sRow) * D_IN
                               + k0 + sCol;
        bf16_t* dst = &Bs[buf][half * 128 * BK + ldsOff];
        load_lds16(src, dst);
        load_lds16(src + (size_t)64 * D_IN, dst + 64 * BK);
    };

    // pipeline fill: tile0 (4 halves) + tile1:A0; drain tile0, keep tile1:A0 flying
    stageA(0, 0, 0); stageA(0, 1, 0); stageB(0, 0, 0); stageB(0, 1, 0);
    stageA(1, 0, 1);
    WAIT_VM2;
    BAR;

    // Steady state per tile t: phases s0..s3 compute quadrants (0,0)(0,1)(1,1)(1,0).
    // Stage stream (1 half-tile/phase, continuous): s0->(t+1)A1, s1->(t+1)B0,
    // s2->(t+1)B1, s3->(t+2)A0.  s3 stages into the buffer being computed: safe,
    // because every ds_read of it drained at s2's lgkmcnt(0) before s2's barrier.
    // vmcnt(2) at s3 = tile t+1 fully landed, (t+2)A0 still in flight.
    // Keep the loop ROLLED: body is already hand-unrolled into 8 phases; -O3
    // full-unroll of 48 iterations produced a pathological compile.
#pragma clang loop unroll(disable)
    for (int t = 0; t < NT; t += 2) {
        // ===== tile t (buf 0) =====
        LOAD_A(0, 0); LOAD_B(0, 0, bq0);            // 12 ds_read_b128
        stageA(t + 1, 1, 1);
        BAR; WAIT_LGKM0; MFMA_Q(0, 0, bq0); BAR;

        LOAD_B(0, 1, bq1);                          // 4
        stageB(t + 1, 0, 1);
        BAR; WAIT_LGKM0; MFMA_Q(0, 1, bq1); BAR;

        LOAD_A(0, 1);                               // 8
        stageB(t + 1, 1, 1);
        BAR; WAIT_LGKM0; MFMA_Q(1, 1, bq1); BAR;

        stageA(t + 2, 0, 0);                        // 0 ds reads; regs already live
        WAIT_VM2;
        BAR; MFMA_Q(1, 0, bq0); BAR;

        // ===== tile t+1 (buf 1) =====
        LOAD_A(1, 0); LOAD_B(1, 0, bq0);
        stageA(t + 2, 1, 0);
        BAR; WAIT_LGKM0; MFMA_Q(0, 0, bq0); BAR;

        LOAD_B(1, 1, bq1);
        stageB(t + 2, 0, 0);
        BAR; WAIT_LGKM0; MFMA_Q(0, 1, bq1); BAR;

        LOAD_A(1, 1);
        stageB(t + 2, 1, 0);
        BAR; WAIT_LGKM0; MFMA_Q(1, 1, bq1); BAR;

        stageA(t + 3, 0, 1);
        WAIT_VM2;
        BAR; MFMA_Q(1, 0, bq0); BAR;
    }

    // C/D: col = lane&15 (N dim), row = quad*4 + reg (M dim)
#pragma unroll
    for (int mi = 0; mi < 8; ++mi)
#pragma unroll
        for (int ni = 0; ni < 4; ++ni) {
            const int col = colBase + wn * 64 + ni * 16 + m16;
            float* up = U + (size_t)(rowBase + wm * 128 + mi * 16 + quad * 4) * D_OUT
                          + col;
#pragma unroll
            for (int r = 0; r < 4; ++r)
                up[(size_t)r * D_OUT] = acc[mi][ni][r];
        }
}

// ---------- Kernel 3: per-row hyperbolic chain, out = Ascale*u + alpha*b (f32) ----------
__global__ __launch_bounds__(256) void pvfc_epilogue(
    const float* __restrict__ U, const float* __restrict__ bvec,
    float* __restrict__ out)
{
    __shared__ float red[12];
    const int row = blockIdx.x, tid = threadIdx.x;
    const int lane = tid & 63, wave = tid >> 6;

    const float* ur = U + (size_t)row * D_OUT + tid * 8;
    float u[8];
    { float4 a = *(const float4*)ur, c = *(const float4*)(ur + 4);
      u[0]=a.x;u[1]=a.y;u[2]=a.z;u[3]=a.w;u[4]=c.x;u[5]=c.y;u[6]=c.z;u[7]=c.w; }
    float b[8];
    { const float* br = bvec + tid * 8;
      float4 a = *(const float4*)br, c = *(const float4*)(br + 4);
      b[0]=a.x;b[1]=a.y;b[2]=a.z;b[3]=a.w;b[4]=c.x;b[5]=c.y;b[6]=c.z;b[7]=c.w; }

    float su2 = 0.f, sub = 0.f, sbb = 0.f;
#pragma unroll
    for (int i = 0; i < 8; ++i) { su2 += u[i]*u[i]; sub += u[i]*b[i]; sbb += b[i]*b[i]; }
#pragma unroll
    for (int off = 32; off > 0; off >>= 1) {
        su2 += __shfl_down(su2, off, 64);
        sub += __shfl_down(sub, off, 64);
        sbb += __shfl_down(sbb, off, 64);
    }
    if (lane == 0) { red[wave] = su2; red[4 + wave] = sub; red[8 + wave] = sbb; }
    __syncthreads();
    su2 = red[0] + red[1] + red[2] + red[3];
    sub = red[4] + red[5] + red[6] + red[7];
    sbb = red[8] + red[9] + red[10] + red[11];

    // scalar chain (f32; verified against reference algebra; C=S=1)
    const float r0 = sqrtf(su2);
    const float t  = fminf(20.f / fmaxf(r0, EPSF), 1.f);    // proj_tan0
    const float rp = t * r0;
    const float coef_e = sinhf(rp) / fmaxf(rp, EPSF);       // exp0
    const float P  = coef_e * t;                            // y = P*u
    const float yn2 = P * P * su2;
    const float beta = 1.f / fmaxf(sqrtf(1.f + yn2), TINYF);
    const float c  = beta / (1.f + beta);                   // pt coef
    const float d  = P * sub;                               // <y,b>
    const float vn2   = sbb + c * d * d * (2.f + c * yn2);  // ||bt||^2
    const float dotxv = d * (1.f + c * yn2);                // <y,bt>
    const float g  = fmaxf(vn2 - dotxv * dotxv / (1.f + yn2), TINYF);
    const float rg = sqrtf(g);
    const float coef1 = beta / (1.f + beta);
    const float t1 = fmaxf(1.f + beta, TINYF);
    const float coef2 = -(beta * beta * beta) / (t1 * t1);
    const float lam = (1.f + beta) / fmaxf(beta, TINYF);
    const float z  = fminf(rg, 20.f);
    const float sc = (fabsf(z) < EPSF) ? (1.f + z * z * (1.f / 6.f))
                                       : (sinhf(z) / fmaxf(z, EPSF));
    const float L = lam * sc;
    const float alpha = L * coef1;                          // w = alpha*b + gamma*y
    const float gamma = L * (coef1 * c * d + coef2 * dotxv);
    const float wn2 = alpha * alpha * sbb + 2.f * alpha * gamma * d + gamma * gamma * yn2;
    const float bw  = 1.f / fmaxf(sqrtf(1.f + wn2), TINYF);
    const float xy  = alpha * d + gamma * yn2;
    const float coefg = coef1 * xy + (1.f - bw) / bw;       // gyro_add coef
    const float Ascale = P * (1.f + gamma + coefg);

    float* orow = out + (size_t)row * D_OUT + tid * 8;
    float4 o0, o1;
    o0.x = Ascale*u[0] + alpha*b[0]; o0.y = Ascale*u[1] + alpha*b[1];
    o0.z = Ascale*u[2] + alpha*b[2]; o0.w = Ascale*u[3] + alpha*b[3];
    o1.x = Ascale*u[4] + alpha*b[4]; o1.y = Ascale*u[5] + alpha*b[5];
    o1.z = Ascale*u[6] + alpha*b[6]; o1.w = Ascale*u[7] + alpha*b[7];
    *(float4*)orow       = o0;
    *(float4*)(orow + 4) = o1;
}

extern "C" void kernel_launch(void* const* d_in, const int* in_sizes, int n_in,
                              void* d_out, int out_size, void* d_ws, size_t ws_size,
                              hipStream_t stream)
{
    const float* x = (const float*)d_in[0];
    const float* W = (const float*)d_in[1];
    const float* b = (const float*)d_in[2];
    float* out = (float*)d_out;

    // ws layout: Wh (8 MiB) | Wl (8 MiB) | per-chunk { A [chunk][4096] bf16 (8KB/row),
    //                                                  U [chunk][2048] f32  (8KB/row) }
    bf16_t* Wh = (bf16_t*)d_ws;
    bf16_t* Wl = Wh + (size_t)D_OUT * D_IN;
    char*   rest = (char*)(Wl + (size_t)D_OUT * D_IN);
    const size_t wbytes = (size_t)D_OUT * D_IN * 2 * 2;           // 16 MiB
    const size_t avail  = (ws_size > wbytes) ? ws_size - wbytes : 0;
    int chunk = (int)((avail / 16384 / 256) * 256);               // rows, multiple of 256
    if (chunk <= 0) chunk = 256;
    if (chunk > N_ROWS) chunk = N_ROWS;

    bf16_t* Ap = (bf16_t*)rest;
    float*  U  = (float*)(rest + (size_t)chunk * (2 * D_IN) * 2);

    pvfc_wsplit<<<(D_OUT * D_IN) / (256 * 8), 256, 0, stream>>>(W, Wh, Wl);
    for (int r0 = 0; r0 < N_ROWS; r0 += chunk) {
        const int rows = (N_ROWS - r0 < chunk) ? (N_ROWS - r0) : chunk;
        pvfc_prologue<<<rows, 256, 0, stream>>>(x + (size_t)r0 * D_IN, Ap);
        pvfc_gemm<<<(rows / 256) * 8, 512, 0, stream>>>(Ap, Wh, Wl, U);
        pvfc_epilogue<<<rows, 256, 0, stream>>>(U, b, out + (size_t)r0 * D_OUT);
    }
}

// Round 4
// 635.539 us; speedup vs baseline: 1.2606x; 1.1353x over previous
//
#include <hip/hip_runtime.h>
#include <stdint.h>

typedef __bf16 bf16_t;
typedef __bf16 bf16x8 __attribute__((ext_vector_type(8)));
typedef float floatx4 __attribute__((ext_vector_type(4)));
typedef float f32x4 __attribute__((ext_vector_type(4)));  // for nontemporal builtins

#define N_ROWS 16384
#define D_IN   2048
#define D_OUT  2048
#define EPSF   1e-6f
#define TINYF  1e-15f

// GEMM geometry: 256x256 tile, BK=64, 8 waves (512 thr), 2-deep LDS double buffer
#define BM 256
#define BN 256
#define BK 64
#define NT 96   // 3 precision segments * (2048/64) k-tiles

// async global->LDS, 16B/lane; LDS base wave-uniform, lane*16 implicit
__device__ __forceinline__ void load_lds16(const void* g, void* l) {
    __builtin_amdgcn_global_load_lds(
        (const __attribute__((address_space(1))) unsigned int*)(const unsigned int*)g,
        (__attribute__((address_space(3))) unsigned int*)(unsigned int*)l,
        16, 0, 0);
}

// ---------- Kernel 0: split W (f32) into bf16 hi/lo planes ----------
__global__ __launch_bounds__(256) void pvfc_wsplit(
    const float* __restrict__ W, bf16_t* __restrict__ Wh, bf16_t* __restrict__ Wl)
{
    const size_t i = ((size_t)blockIdx.x * 256 + threadIdx.x) * 8;
    f32x4 a = *(const f32x4*)(W + i);
    f32x4 c = *(const f32x4*)(W + i + 4);
    float v[8] = {a.x, a.y, a.z, a.w, c.x, c.y, c.z, c.w};
    bf16x8 hv, lv;
#pragma unroll
    for (int j = 0; j < 8; ++j) {
        const bf16_t h = (bf16_t)v[j];
        hv[j] = h;
        lv[j] = (bf16_t)(v[j] - (float)h);
    }
    *(bf16x8*)(Wh + i) = hv;
    *(bf16x8*)(Wl + i) = lv;
}

// ---------- Kernel 1: v = asinh(||x||)/||x|| * x, split into bf16 hi/lo ----------
// A layout: [rows][4096] bf16 : cols 0..2047 = v_hi, 2048..4095 = v_lo
__global__ __launch_bounds__(256) void pvfc_prologue(
    const float* __restrict__ x, bf16_t* __restrict__ Ap)
{
    __shared__ float red[4];
    const int row = blockIdx.x, tid = threadIdx.x;
    const int lane = tid & 63, wave = tid >> 6;

    const float* xr = x + (size_t)row * D_IN + tid * 8;
    f32x4 a = __builtin_nontemporal_load((const f32x4*)xr);
    f32x4 c = __builtin_nontemporal_load((const f32x4*)(xr + 4));
    float v[8] = {a.x, a.y, a.z, a.w, c.x, c.y, c.z, c.w};

    float s = 0.f;
#pragma unroll
    for (int i = 0; i < 8; ++i) s += v[i] * v[i];
#pragma unroll
    for (int off = 32; off > 0; off >>= 1) s += __shfl_down(s, off, 64);
    if (lane == 0) red[wave] = s;
    __syncthreads();
    const float s2  = red[0] + red[1] + red[2] + red[3];
    const float nrm = sqrtf(s2);
    const float coef = asinhf(nrm) / fmaxf(nrm, EPSF);

    bf16x8 hv, lv;
#pragma unroll
    for (int j = 0; j < 8; ++j) {
        const float vi = coef * v[j];
        const bf16_t h = (bf16_t)vi;
        hv[j] = h;
        lv[j] = (bf16_t)(vi - (float)h);
    }
    bf16_t* ar = Ap + (size_t)row * (2 * D_IN);
    *(bf16x8*)(ar + tid * 8)         = hv;   // cached: gemm re-reads A via L3
    *(bf16x8*)(ar + D_IN + tid * 8)  = lv;
}

// ---------- Kernel 2: U = Ah.Wh^T + Al.Wh^T + Ah.Wl^T ----------
// One barrier per K-tile; whole-tile register prefetch (24 x ds_read_b128/wave).
// Waves free-run within a tile -> LDS-pipe bursts of one wave overlap MFMA bursts
// of another (the round-2 counters showed barrier-forced alternation: MfmaUtil 38%,
// LDS ~2300cyc vs MFMA ~2060cyc per tile, serialized by 8 barriers/tile).
// Staging (next tile -> other buffer) issues at tile top; vmcnt(0) at tile end is
// ~free (issued a full tile earlier). T2 swizzle + T5 setprio retained.
#define BAR __builtin_amdgcn_s_barrier()
#define SCHED_FENCE __builtin_amdgcn_sched_barrier(0)
#define WAIT_VM0 do { asm volatile("s_waitcnt vmcnt(0)" ::: "memory"); \
                      __builtin_amdgcn_sched_barrier(0); } while (0)

#define LOAD_AH(buf, qm, AF)                                                   \
    _Pragma("unroll")                                                          \
    for (int i = 0; i < 4; ++i) {                                              \
        const int rA = wm * 128 + ((qm) * 4 + i) * 16 + m16;                   \
        _Pragma("unroll")                                                      \
        for (int ks = 0; ks < 2; ++ks)                                         \
            AF[i][ks] = *(const bf16x8*)&As[buf][rA * BK +                     \
                                                 (((ks * 4 + quad) ^ sw) * 8)];\
    }

#define LOAD_B(buf, qn, bq)                                                    \
    _Pragma("unroll")                                                          \
    for (int j = 0; j < 2; ++j) {                                              \
        const int rB = wn * 64 + ((qn) * 2 + j) * 16 + m16;                    \
        _Pragma("unroll")                                                      \
        for (int ks = 0; ks < 2; ++ks)                                         \
            bq[j][ks] = *(const bf16x8*)&Bs[buf][rB * BK +                     \
                                                 (((ks * 4 + quad) ^ sw) * 8)];\
    }

#define MFMA_Q(AF, BQ, qm, qn)                                                 \
    do {                                                                       \
        __builtin_amdgcn_s_setprio(1);                                         \
        _Pragma("unroll")                                                      \
        for (int ks = 0; ks < 2; ++ks)                                         \
            _Pragma("unroll")                                                  \
            for (int i = 0; i < 4; ++i)                                        \
                _Pragma("unroll")                                              \
                for (int j = 0; j < 2; ++j)                                    \
                    acc[(qm) * 4 + i][(qn) * 2 + j] =                          \
                        __builtin_amdgcn_mfma_f32_16x16x32_bf16(               \
                            AF[i][ks], BQ[j][ks],                              \
                            acc[(qm) * 4 + i][(qn) * 2 + j], 0, 0, 0);         \
        __builtin_amdgcn_s_setprio(0);                                         \
    } while (0)

// Per-tile body: read buf rb, stage tile st into buf sb, ONE barrier at end.
// Hazard ledger: RAW(stage->read): my 8 staging loads drain at WAIT_VM0 before
// BAR; reads of sb happen after BAR. WAR(read->stage): stage of sb issues after
// the barrier that followed the tile whose MFMAs consumed all reads of sb
// (compiler lgkm waits pin read completion before those MFMAs, which precede
// the barrier). All waves symmetric -> uniform barrier count.
#define TILE_BODY(rb, sb, st)                                                  \
    do {                                                                       \
        stageA(st, 0, sb); stageA(st, 1, sb);                                  \
        stageB(st, 0, sb); stageB(st, 1, sb);                                  \
        SCHED_FENCE;                                                           \
        LOAD_AH(rb, 0, afA); LOAD_B(rb, 0, bq0); LOAD_B(rb, 1, bq1);           \
        SCHED_FENCE;                                                           \
        MFMA_Q(afA, bq0, 0, 0);                                                \
        SCHED_FENCE;                                                           \
        LOAD_AH(rb, 1, afB);                                                   \
        SCHED_FENCE;                                                           \
        MFMA_Q(afA, bq1, 0, 1);                                                \
        MFMA_Q(afB, bq1, 1, 1);                                                \
        MFMA_Q(afB, bq0, 1, 0);                                                \
        WAIT_VM0;                                                              \
        BAR;                                                                   \
    } while (0)

__global__ __launch_bounds__(512, 2) void pvfc_gemm(
    const bf16_t* __restrict__ A,   // [rows][4096] hi|lo
    const bf16_t* __restrict__ Wh, const bf16_t* __restrict__ Wl, // [2048][2048]
    float* __restrict__ U)          // [rows][2048] f32
{
    __shared__ __align__(16) bf16_t As[2][BM * BK];  // 64 KiB
    __shared__ __align__(16) bf16_t Bs[2][BN * BK];  // 64 KiB

    const int tid  = threadIdx.x;
    const int wave = tid >> 6, lane = tid & 63;
    const int bid  = blockIdx.x;
    const int colBase = (bid & 7) * BN;   // bid%8 == XCD: W panel L2-resident
    const int rowBase = (bid >> 3) * BM;

    const int wm = wave >> 2, wn = wave & 3;        // 2x4 wave grid, 128x64/wave
    const int m16 = lane & 15, quad = lane >> 4;
    const int sw  = m16 & 7;                        // read-side xor key

    // staging: 512 threads cover 64 rows x 128B per load; src pre-swizzled
    const int sRow = tid >> 3;                      // 0..63
    const int sCol = ((tid & 7) ^ (sRow & 7)) * 8;  // logical chunk for linear dest
    const int ldsOff = wave * 512;                  // wave-uniform dest (elements)

    floatx4 acc[8][4];
    bf16x8 afA[4][2], afB[4][2], bq0[2][2], bq1[2][2];
    const floatx4 z = {0.f, 0.f, 0.f, 0.f};
#pragma unroll
    for (int i = 0; i < 8; ++i)
#pragma unroll
        for (int j = 0; j < 4; ++j) acc[i][j] = z;

    // half-tile stagers (2 x global_load_lds each); tile clamped at tail (writes
    // land in a buffer that is never read again -> safe, addresses in-bounds)
    auto stageA = [&](int tile, int half, int buf) {
        const int tt  = tile < NT ? tile : NT - 1;
        const int seg = tt >> 5;                    // 0:(Ah,Wh) 1:(Al,Wh) 2:(Ah,Wl)
        const size_t off = (size_t)((seg == 1) ? D_IN : 0) + (size_t)(tt & 31) * BK;
        const bf16_t* src = A + (size_t)(rowBase + half * 128 + sRow) * (2 * D_IN)
                              + off + sCol;
        bf16_t* dst = &As[buf][half * 128 * BK + ldsOff];
        load_lds16(src, dst);
        load_lds16(src + (size_t)64 * (2 * D_IN), dst + 64 * BK);
    };
    auto stageB = [&](int tile, int half, int buf) {
        const int tt  = tile < NT ? tile : NT - 1;
        const bf16_t* Wp = ((tt >> 5) == 2) ? Wl : Wh;
        const int k0 = (tt & 31) * BK;
        const bf16_t* src = Wp + (size_t)(colBase + half * 128 + sRow) * D_IN
                               + k0 + sCol;
        bf16_t* dst = &Bs[buf][half * 128 * BK + ldsOff];
        load_lds16(src, dst);
        load_lds16(src + (size_t)64 * D_IN, dst + 64 * BK);
    };

    // pipeline fill: tile0 -> buf0, drain, publish
    stageA(0, 0, 0); stageA(0, 1, 0); stageB(0, 0, 0); stageB(0, 1, 0);
    WAIT_VM0;
    BAR;

    // Keep the outer loop ROLLED (x2 unrolled body for static buf index);
    // -O3 full-unroll of 48 iterations produced a pathological compile.
#pragma clang loop unroll(disable)
    for (int t = 0; t < NT; t += 2) {
        TILE_BODY(0, 1, t + 1);   // compute tile t   (buf0), stage t+1 -> buf1
        TILE_BODY(1, 0, t + 2);   // compute tile t+1 (buf1), stage t+2 -> buf0
    }

    // C/D: col = lane&15 (N dim), row = quad*4 + reg (M dim).
    // Nontemporal: U streams (134 MB) would thrash L3 and evict A (the round-2
    // FETCH_SIZE=812MB anomaly: A+W+U = 284MB > 256MB L3).
#pragma unroll
    for (int mi = 0; mi < 8; ++mi)
#pragma unroll
        for (int ni = 0; ni < 4; ++ni) {
            const int col = colBase + wn * 64 + ni * 16 + m16;
            float* up = U + (size_t)(rowBase + wm * 128 + mi * 16 + quad * 4) * D_OUT
                          + col;
#pragma unroll
            for (int r = 0; r < 4; ++r)
                __builtin_nontemporal_store(acc[mi][ni][r], up + (size_t)r * D_OUT);
        }
}

// ---------- Kernel 3: per-row hyperbolic chain, out = Ascale*u + alpha*b (f32) ----------
__global__ __launch_bounds__(256) void pvfc_epilogue(
    const float* __restrict__ U, const float* __restrict__ bvec,
    float* __restrict__ out)
{
    __shared__ float red[12];
    const int row = blockIdx.x, tid = threadIdx.x;
    const int lane = tid & 63, wave = tid >> 6;

    const float* ur = U + (size_t)row * D_OUT + tid * 8;
    float u[8];
    { f32x4 a = __builtin_nontemporal_load((const f32x4*)ur);
      f32x4 c = __builtin_nontemporal_load((const f32x4*)(ur + 4));
      u[0]=a.x;u[1]=a.y;u[2]=a.z;u[3]=a.w;u[4]=c.x;u[5]=c.y;u[6]=c.z;u[7]=c.w; }
    float b[8];
    { const float* br = bvec + tid * 8;
      f32x4 a = *(const f32x4*)br, c = *(const f32x4*)(br + 4);
      b[0]=a.x;b[1]=a.y;b[2]=a.z;b[3]=a.w;b[4]=c.x;b[5]=c.y;b[6]=c.z;b[7]=c.w; }

    float su2 = 0.f, sub = 0.f, sbb = 0.f;
#pragma unroll
    for (int i = 0; i < 8; ++i) { su2 += u[i]*u[i]; sub += u[i]*b[i]; sbb += b[i]*b[i]; }
#pragma unroll
    for (int off = 32; off > 0; off >>= 1) {
        su2 += __shfl_down(su2, off, 64);
        sub += __shfl_down(sub, off, 64);
        sbb += __shfl_down(sbb, off, 64);
    }
    if (lane == 0) { red[wave] = su2; red[4 + wave] = sub; red[8 + wave] = sbb; }
    __syncthreads();
    su2 = red[0] + red[1] + red[2] + red[3];
    sub = red[4] + red[5] + red[6] + red[7];
    sbb = red[8] + red[9] + red[10] + red[11];

    // scalar chain (f32; verified against reference algebra; C=S=1)
    const float r0 = sqrtf(su2);
    const float t  = fminf(20.f / fmaxf(r0, EPSF), 1.f);    // proj_tan0
    const float rp = t * r0;
    const float coef_e = sinhf(rp) / fmaxf(rp, EPSF);       // exp0
    const float P  = coef_e * t;                            // y = P*u
    const float yn2 = P * P * su2;
    const float beta = 1.f / fmaxf(sqrtf(1.f + yn2), TINYF);
    const float c  = beta / (1.f + beta);                   // pt coef
    const float d  = P * sub;                               // <y,b>
    const float vn2   = sbb + c * d * d * (2.f + c * yn2);  // ||bt||^2
    const float dotxv = d * (1.f + c * yn2);                // <y,bt>
    const float g  = fmaxf(vn2 - dotxv * dotxv / (1.f + yn2), TINYF);
    const float rg = sqrtf(g);
    const float coef1 = beta / (1.f + beta);
    const float t1 = fmaxf(1.f + beta, TINYF);
    const float coef2 = -(beta * beta * beta) / (t1 * t1);
    const float lam = (1.f + beta) / fmaxf(beta, TINYF);
    const float z  = fminf(rg, 20.f);
    const float sc = (fabsf(z) < EPSF) ? (1.f + z * z * (1.f / 6.f))
                                       : (sinhf(z) / fmaxf(z, EPSF));
    const float L = lam * sc;
    const float alpha = L * coef1;                          // w = alpha*b + gamma*y
    const float gamma = L * (coef1 * c * d + coef2 * dotxv);
    const float wn2 = alpha * alpha * sbb + 2.f * alpha * gamma * d + gamma * gamma * yn2;
    const float bw  = 1.f / fmaxf(sqrtf(1.f + wn2), TINYF);
    const float xy  = alpha * d + gamma * yn2;
    const float coefg = coef1 * xy + (1.f - bw) / bw;       // gyro_add coef
    const float Ascale = P * (1.f + gamma + coefg);

    float* orow = out + (size_t)row * D_OUT + tid * 8;
    f32x4 o0, o1;
    o0.x = Ascale*u[0] + alpha*b[0]; o0.y = Ascale*u[1] + alpha*b[1];
    o0.z = Ascale*u[2] + alpha*b[2]; o0.w = Ascale*u[3] + alpha*b[3];
    o1.x = Ascale*u[4] + alpha*b[4]; o1.y = Ascale*u[5] + alpha*b[5];
    o1.z = Ascale*u[6] + alpha*b[6]; o1.w = Ascale*u[7] + alpha*b[7];
    __builtin_nontemporal_store(o0, (f32x4*)orow);
    __builtin_nontemporal_store(o1, (f32x4*)(orow + 4));
}

extern "C" void kernel_launch(void* const* d_in, const int* in_sizes, int n_in,
                              void* d_out, int out_size, void* d_ws, size_t ws_size,
                              hipStream_t stream)
{
    const float* x = (const float*)d_in[0];
    const float* W = (const float*)d_in[1];
    const float* b = (const float*)d_in[2];
    float* out = (float*)d_out;

    // ws layout: Wh (8 MiB) | Wl (8 MiB) | per-chunk { A [chunk][4096] bf16 (8KB/row),
    //                                                  U [chunk][2048] f32  (8KB/row) }
    bf16_t* Wh = (bf16_t*)d_ws;
    bf16_t* Wl = Wh + (size_t)D_OUT * D_IN;
    char*   rest = (char*)(Wl + (size_t)D_OUT * D_IN);
    const size_t wbytes = (size_t)D_OUT * D_IN * 2 * 2;           // 16 MiB
    const size_t avail  = (ws_size > wbytes) ? ws_size - wbytes : 0;
    int chunk = (int)((avail / 16384 / 256) * 256);               // rows, multiple of 256
    if (chunk <= 0) chunk = 256;
    if (chunk > N_ROWS) chunk = N_ROWS;

    bf16_t* Ap = (bf16_t*)rest;
    float*  U  = (float*)(rest + (size_t)chunk * (2 * D_IN) * 2);

    pvfc_wsplit<<<(D_OUT * D_IN) / (256 * 8), 256, 0, stream>>>(W, Wh, Wl);
    for (int r0 = 0; r0 < N_ROWS; r0 += chunk) {
        const int rows = (N_ROWS - r0 < chunk) ? (N_ROWS - r0) : chunk;
        pvfc_prologue<<<rows, 256, 0, stream>>>(x + (size_t)r0 * D_IN, Ap);
        pvfc_gemm<<<dim3(D_OUT / BN * (rows / BM)), 512, 0, stream>>>(Ap, Wh, Wl, U);
        pvfc_epilogue<<<rows, 256, 0, stream>>>(U, b, out + (size_t)r0 * D_OUT);
    }
}